// Round 2
// baseline (69.086 us; speedup 1.0000x reference)
//
#include <hip/hip_runtime.h>

// Quantum classifier, 20 qubits, depth-2 hardware-efficient ansatz.
//
// ANALYTIC REDUCTION (Heisenberg picture / Pauli back-propagation):
// The measured feature for qubit q is -<Z_q> of the final state. Conjugating
// Z_q backward through U = CZ . RY(th1) . CZ . RY(th0) . RX(x):
//   1) CZ layer (diagonal) commutes with Z_q              -> Z_q
//   2) RY(th1): Z_q -> cos(t1q) Z_q - sin(t1q) X_q
//   3) CZ chain: Z_q -> Z_q ;  X_q -> Z_{q-1} X_q Z_{q+1}  (clip at ends)
//   4) RY(th0): Z_j -> cos(t0j) Z_j - sin(t0j) X_j   (neighbors: Z operators)
//              X_j -> sin(t0j) Z_j + cos(t0j) X_j   (center: X operator)
//   5) RX(x) on |0>^n (product state): <Z_j> = cos(x_j), <X_j> = 0,
//      and tensor-product expectations factor.
// So:
//   <Z_q> = cos(t1q) cos(t0q) cos(x_q)
//         - sin(t1q) sin(t0q) cos(x_q) * PROD_{j in nbrs(q)} cos(t0j) cos(x_j)
//   features[b,q] = -<Z_q>,  logits = features @ W^T + b.
// (Round-1 bug: neighbor factor used sin(t0j) instead of cos(t0j) — the
//  X-row transform was applied to a Z operator. n=1 reduction cos(t0+t1)cosx
//  verifies the corrected form.)
// Exact for all inputs; only fp32 trig rounding remains (~1e-6 absmax).

#define N_QUBITS 20

__global__ __launch_bounds__(64) void qc_analytic_kernel(
    const float* __restrict__ x,      // (32, 20)
    const float* __restrict__ theta,  // (2, 20)  theta0=theta[q], theta1=theta[20+q]
    const float* __restrict__ W,      // (2, 20)
    const float* __restrict__ bias,   // (2,)
    float* __restrict__ out)          // (32, 2)
{
    const int t = threadIdx.x;   // 0..63
    const int bidx = t >> 1;     // batch element 0..31
    const int k = t & 1;         // output class 0..1

    const float* xb = x + bidx * N_QUBITS;

    float c[N_QUBITS];    // cos(x_bq)
    float cc[N_QUBITS];   // cos(theta0_q) * cos(x_bq)   (neighbor factor)
#pragma unroll
    for (int q = 0; q < N_QUBITS; ++q) {
        c[q]  = cosf(xb[q]);
        cc[q] = cosf(theta[q]) * c[q];
    }

    float acc = bias[k];
#pragma unroll
    for (int q = 0; q < N_QUBITS; ++q) {
        const float t0 = theta[q];
        const float t1 = theta[N_QUBITS + q];
        float prod = 1.0f;
        if (q > 0)            prod *= cc[q - 1];
        if (q < N_QUBITS - 1) prod *= cc[q + 1];
        const float z = cosf(t1) * cosf(t0) * c[q]
                      - sinf(t1) * sinf(t0) * c[q] * prod;
        acc += (-z) * W[k * N_QUBITS + q];
    }

    out[bidx * 2 + k] = acc;
}

extern "C" void kernel_launch(void* const* d_in, const int* in_sizes, int n_in,
                              void* d_out, int out_size, void* d_ws, size_t ws_size,
                              hipStream_t stream) {
    const float* x     = (const float*)d_in[0];  // 32*20
    const float* theta = (const float*)d_in[1];  // 2*20
    const float* W     = (const float*)d_in[2];  // 2*20
    const float* bias  = (const float*)d_in[3];  // 2
    float* out = (float*)d_out;                  // 64

    qc_analytic_kernel<<<1, 64, 0, stream>>>(x, theta, W, bias, out);
}